// Round 1
// baseline (190.933 us; speedup 1.0000x reference)
//
#include <hip/hip_runtime.h>

typedef __attribute__((ext_vector_type(8))) short bh8;   // 8 bf16 (4 VGPRs)
typedef __attribute__((ext_vector_type(4))) float f32x4; // 4 fp32 acc
typedef unsigned short u16;

#define MFMA16 __builtin_amdgcn_mfma_f32_16x16x32_bf16

__device__ __forceinline__ u16 f2bf(float f) {
  union { float f; unsigned u; } v; v.f = f;
  unsigned r = v.u + 0x7fffu + ((v.u >> 16) & 1u);
  return (u16)(r >> 16);
}

__device__ __forceinline__ void gload16(void* lds, const void* g) {
  __builtin_amdgcn_global_load_lds(
      (const __attribute__((address_space(1))) unsigned int*)g,
      (__attribute__((address_space(3))) unsigned int*)lds, 16, 0, 0);
}

// ---------------- LayerNorm: one wave per row of 512 fp32 -> bf16 ----------
__global__ __launch_bounds__(256) void k_ln(const float* __restrict__ x,
                                            const float* __restrict__ gamma,
                                            const float* __restrict__ beta,
                                            u16* __restrict__ xn) {
  int row  = blockIdx.x * 4 + (threadIdx.x >> 6);
  int lane = threadIdx.x & 63;
  const float4* xr = (const float4*)(x + row * 512);
  float4 a = xr[lane * 2], b = xr[lane * 2 + 1];
  float s  = a.x + a.y + a.z + a.w + b.x + b.y + b.z + b.w;
  float ss = a.x*a.x + a.y*a.y + a.z*a.z + a.w*a.w
           + b.x*b.x + b.y*b.y + b.z*b.z + b.w*b.w;
#pragma unroll
  for (int m = 1; m < 64; m <<= 1) { s += __shfl_xor(s, m, 64); ss += __shfl_xor(ss, m, 64); }
  float mu  = s * (1.0f / 512.0f);
  float var = ss * (1.0f / 512.0f) - mu * mu;
  float rstd = rsqrtf(var + 1e-5f);
  const float4* g4 = (const float4*)gamma;
  const float4* b4 = (const float4*)beta;
  float4 g0 = g4[lane * 2], g1 = g4[lane * 2 + 1];
  float4 e0 = b4[lane * 2], e1 = b4[lane * 2 + 1];
  bh8 ov;
  ov[0] = (short)f2bf((a.x - mu) * rstd * g0.x + e0.x);
  ov[1] = (short)f2bf((a.y - mu) * rstd * g0.y + e0.y);
  ov[2] = (short)f2bf((a.z - mu) * rstd * g0.z + e0.z);
  ov[3] = (short)f2bf((a.w - mu) * rstd * g0.w + e0.w);
  ov[4] = (short)f2bf((b.x - mu) * rstd * g1.x + e1.x);
  ov[5] = (short)f2bf((b.y - mu) * rstd * g1.y + e1.y);
  ov[6] = (short)f2bf((b.z - mu) * rstd * g1.z + e1.z);
  ov[7] = (short)f2bf((b.w - mu) * rstd * g1.w + e1.w);
  *(bh8*)(xn + row * 512 + lane * 8) = ov;
}

// -------- transpose + cast: in (R,C) f32 row-major -> out (C,R) bf16 -------
__global__ __launch_bounds__(256) void k_transpose_cast(const float* __restrict__ in,
                                                        u16* __restrict__ out,
                                                        int R, int C) {
  __shared__ float tile[32][33];
  int c0 = blockIdx.x * 32, r0 = blockIdx.y * 32;
  int tx = threadIdx.x & 31, ty = threadIdx.x >> 5;
#pragma unroll
  for (int i = 0; i < 32; i += 8)
    tile[ty + i][tx] = in[(r0 + ty + i) * C + (c0 + tx)];
  __syncthreads();
#pragma unroll
  for (int i = 0; i < 32; i += 8)
    out[(c0 + ty + i) * R + (r0 + tx)] = f2bf(tile[tx][ty + i]);
}

// ---------------- V [bh][t][d] -> Vt [bh][d][t] ----------------------------
__global__ __launch_bounds__(256) void k_repack_vt(const u16* __restrict__ V,
                                                   u16* __restrict__ Vt) {
  __shared__ u16 tile[64 * 64];
  int bh = blockIdx.y;
  int t0 = blockIdx.x * 64;
  int tid = threadIdx.x;
  const u16* src = V + (bh * 4096 + t0) * 64;
#pragma unroll
  for (int j = 0; j < 2; ++j)
    *(bh8*)&tile[(j * 256 + tid) * 8] = *(const bh8*)(src + (j * 256 + tid) * 8);
  __syncthreads();
  int d = tid >> 2, ts = (tid & 3) * 16;
  bh8 o0, o1;
#pragma unroll
  for (int e = 0; e < 8; ++e) {
    o0[e] = (short)tile[(ts + e) * 64 + d];
    o1[e] = (short)tile[(ts + 8 + e) * 64 + d];
  }
  u16* dst = Vt + (bh * 64 + d) * 4096 + t0 + ts;
  *(bh8*)dst = o0;
  *(bh8*)(dst + 8) = o1;
}

// ---------------- GEMM: A (M,512) bf16 @ Bt (N,512) bf16 -------------------
// BM=128 BN=128 BK=64, 4 waves, each wave 64x64 (4x4 16x16 frags).
// LDS XOR-swizzle (row&7)<<4 bytes applied on global source (linear LDS dest)
// and on the ds_read side, so ds_read_b128 is ~conflict-free.
// EPI=0: scatter q/k/v bf16 [bh][t][d].  EPI=1: +bias +residual, f32 out.
template <int EPI>
__global__ __launch_bounds__(256) void k_gemm(const u16* __restrict__ A,
                                              const u16* __restrict__ Bt,
                                              int N,
                                              u16* __restrict__ q, u16* __restrict__ kk, u16* __restrict__ v,
                                              const float* __restrict__ bias,
                                              const float* __restrict__ resid,
                                              float* __restrict__ outp) {
  constexpr int K = 512, BM = 128, BK = 64;
  __shared__ u16 Al[BM * BK];
  __shared__ u16 Bl[BM * BK];
  int nBN = N / 128;
  int m0 = (blockIdx.x / nBN) * BM;
  int n0 = (blockIdx.x % nBN) * 128;
  int tid = threadIdx.x, lane = tid & 63, w = tid >> 6;
  int l16 = lane & 15, lh = lane >> 4;
  int wm = (w >> 1) * 64, wn = (w & 1) * 64;
  const u16* Ab = A + m0 * K;
  const u16* Bb = Bt + n0 * K;
  f32x4 acc[4][4];
#pragma unroll
  for (int i = 0; i < 4; ++i)
#pragma unroll
    for (int j = 0; j < 4; ++j) acc[i][j] = (f32x4){0.f, 0.f, 0.f, 0.f};
  int srow = tid >> 3, schunk = tid & 7;
  for (int k0 = 0; k0 < K; k0 += BK) {
    __syncthreads();
#pragma unroll
    for (int j = 0; j < 4; ++j) {
      int r = j * 32 + srow;
      int sc = ((schunk ^ (r & 7)) << 3);
      gload16((char*)Al + j * 4096 + tid * 16, Ab + r * K + k0 + sc);
      gload16((char*)Bl + j * 4096 + tid * 16, Bb + r * K + k0 + sc);
    }
    __syncthreads();
#pragma unroll
    for (int c = 0; c < 2; ++c) {
      bh8 af[4], bf[4];
#pragma unroll
      for (int i = 0; i < 4; ++i) {
        int ra = wm + i * 16 + l16;
        af[i] = *(const bh8*)&Al[ra * 64 + ((c * 32 + lh * 8) ^ ((ra & 7) << 3))];
        int rb = wn + i * 16 + l16;
        bf[i] = *(const bh8*)&Bl[rb * 64 + ((c * 32 + lh * 8) ^ ((rb & 7) << 3))];
      }
#pragma unroll
      for (int mi = 0; mi < 4; ++mi)
#pragma unroll
        for (int ni = 0; ni < 4; ++ni)
          acc[mi][ni] = MFMA16(af[mi], bf[ni], acc[mi][ni], 0, 0, 0);
    }
  }
  if (EPI == 0) {
#pragma unroll
    for (int mi = 0; mi < 4; ++mi)
#pragma unroll
      for (int ni = 0; ni < 4; ++ni) {
        int col = n0 + wn + ni * 16 + l16;
        int s = col >> 9, h = (col >> 6) & 7, d = col & 63;
        u16* base = (s == 0 ? q : (s == 1 ? kk : v));
#pragma unroll
        for (int j = 0; j < 4; ++j) {
          int row = m0 + wm + mi * 16 + lh * 4 + j;
          int b = row >> 12, t = row & 4095;
          base[(((b << 3) + h) * 4096 + t) * 64 + d] = f2bf(acc[mi][ni][j]);
        }
      }
  } else {
#pragma unroll
    for (int mi = 0; mi < 4; ++mi)
#pragma unroll
      for (int ni = 0; ni < 4; ++ni) {
        int col = n0 + wn + ni * 16 + l16;
        float bo = bias[col];
#pragma unroll
        for (int j = 0; j < 4; ++j) {
          int row = m0 + wm + mi * 16 + lh * 4 + j;
          outp[row * 512 + col] = acc[mi][ni][j] + bo + resid[row * 512 + col];
        }
      }
  }
}

// ---------------- Flash attention, causal, hd=64 ---------------------------
// block = 4 waves; Q tile = 64 rows (16/wave); KV tile = 64.
// S = mfma(Q, K^T): C rows = tq (lh*4+j), cols = tk (f*16+l16).
// Softmax row-stats: 4-reg local + shfl_xor(1,2,4,8) within 16-lane group.
// P bounced through per-wave swizzled LDS -> A-fragment for PV.
__global__ __launch_bounds__(256) void k_attn(const u16* __restrict__ Q,
                                              const u16* __restrict__ Kg,
                                              const u16* __restrict__ Vt,
                                              u16* __restrict__ O) {
  __shared__ u16 Kl[64 * 64];
  __shared__ u16 Vl[64 * 64];
  __shared__ u16 Pl[4 * 16 * 64];
  int bh = blockIdx.x & 15;
  int qi = 63 - (blockIdx.x >> 4);   // descending length for load balance
  int tid = threadIdx.x, lane = tid & 63, w = tid >> 6;
  int l16 = lane & 15, lh = lane >> 4;
  const u16* Qb = Q + bh * 4096 * 64;
  const u16* Kb = Kg + bh * 4096 * 64;
  const u16* Vb = Vt + bh * 64 * 4096;
  int q0 = qi * 64;
  int qrow = q0 + w * 16 + l16;
  bh8 qf0 = *(const bh8*)(Qb + qrow * 64 + lh * 8);
  bh8 qf1 = *(const bh8*)(Qb + qrow * 64 + 32 + lh * 8);
  float m_[4] = {-3e38f, -3e38f, -3e38f, -3e38f};
  float l_[4] = {0.f, 0.f, 0.f, 0.f};
  f32x4 acc[4];
#pragma unroll
  for (int dn = 0; dn < 4; ++dn) acc[dn] = (f32x4){0.f, 0.f, 0.f, 0.f};
  int srow = tid >> 3, schunk = tid & 7;
  for (int kt = 0; kt <= qi; ++kt) {
    int k0 = kt * 64;
    __syncthreads();
#pragma unroll
    for (int j = 0; j < 2; ++j) {
      int r = j * 32 + srow;
      int sc = ((schunk ^ (r & 7)) << 3);
      gload16((char*)Kl + j * 4096 + tid * 16, Kb + (k0 + r) * 64 + sc);
      gload16((char*)Vl + j * 4096 + tid * 16, Vb + r * 4096 + k0 + sc);
    }
    __syncthreads();
    f32x4 s[4];
#pragma unroll
    for (int f = 0; f < 4; ++f) {
      int r = f * 16 + l16;
      bh8 kf0 = *(const bh8*)&Kl[r * 64 + ((lh * 8) ^ ((r & 7) << 3))];
      bh8 kf1 = *(const bh8*)&Kl[r * 64 + ((32 + lh * 8) ^ ((r & 7) << 3))];
      f32x4 z = (f32x4){0.f, 0.f, 0.f, 0.f};
      z = MFMA16(qf0, kf0, z, 0, 0, 0);
      z = MFMA16(qf1, kf1, z, 0, 0, 0);
      s[f] = z;
    }
    if (kt == qi) {
#pragma unroll
      for (int f = 0; f < 4; ++f)
#pragma unroll
        for (int j = 0; j < 4; ++j) {
          int col = k0 + f * 16 + l16;
          int row = q0 + w * 16 + lh * 4 + j;
          if (col > row) s[f][j] = -3e38f;
        }
    }
    float mx[4], rsum[4];
#pragma unroll
    for (int j = 0; j < 4; ++j)
      mx[j] = fmaxf(fmaxf(s[0][j], s[1][j]), fmaxf(s[2][j], s[3][j]));
#pragma unroll
    for (int msk = 1; msk < 16; msk <<= 1)
#pragma unroll
      for (int j = 0; j < 4; ++j)
        mx[j] = fmaxf(mx[j], __shfl_xor(mx[j], msk, 64));
    u16* pw = Pl + w * 1024;
#pragma unroll
    for (int j = 0; j < 4; ++j) {
      float nm = fmaxf(m_[j], mx[j]);
      float sc = __expf((m_[j] - nm) * 0.125f);
      m_[j] = nm;
      l_[j] *= sc;
#pragma unroll
      for (int dn = 0; dn < 4; ++dn) acc[dn][j] *= sc;
      float r = 0.f;
#pragma unroll
      for (int f = 0; f < 4; ++f) {
        float p = __expf((s[f][j] - nm) * 0.125f);
        s[f][j] = p;
        r += p;
      }
      rsum[j] = r;
    }
#pragma unroll
    for (int msk = 1; msk < 16; msk <<= 1)
#pragma unroll
      for (int j = 0; j < 4; ++j)
        rsum[j] += __shfl_xor(rsum[j], msk, 64);
#pragma unroll
    for (int j = 0; j < 4; ++j) l_[j] += rsum[j];
#pragma unroll
    for (int j = 0; j < 4; ++j) {
      int r = lh * 4 + j;
#pragma unroll
      for (int f = 0; f < 4; ++f)
        pw[r * 64 + ((f * 16 + l16) ^ ((r & 7) << 3))] = f2bf(s[f][j]);
    }
    __syncthreads();
    bh8 pa0 = *(const bh8*)&pw[l16 * 64 + ((lh * 8) ^ ((l16 & 7) << 3))];
    bh8 pa1 = *(const bh8*)&pw[l16 * 64 + ((32 + lh * 8) ^ ((l16 & 7) << 3))];
#pragma unroll
    for (int dn = 0; dn < 4; ++dn) {
      int r = dn * 16 + l16;
      bh8 v0 = *(const bh8*)&Vl[r * 64 + ((lh * 8) ^ ((r & 7) << 3))];
      bh8 v1 = *(const bh8*)&Vl[r * 64 + ((32 + lh * 8) ^ ((r & 7) << 3))];
      acc[dn] = MFMA16(pa0, v0, acc[dn], 0, 0, 0);
      acc[dn] = MFMA16(pa1, v1, acc[dn], 0, 0, 0);
    }
  }
  int b = bh >> 3, h = bh & 7;
#pragma unroll
  for (int j = 0; j < 4; ++j) {
    float inv = 1.0f / l_[j];
    int t = q0 + w * 16 + lh * 4 + j;
#pragma unroll
    for (int dn = 0; dn < 4; ++dn)
      O[(b * 4096 + t) * 512 + h * 64 + dn * 16 + l16] = f2bf(acc[dn][j] * inv);
  }
}

extern "C" void kernel_launch(void* const* d_in, const int* in_sizes, int n_in,
                              void* d_out, int out_size, void* d_ws, size_t ws_size,
                              hipStream_t stream) {
  const float* x     = (const float*)d_in[0];
  const float* w_qkv = (const float*)d_in[1];
  const float* w_out = (const float*)d_in[2];
  const float* b_out = (const float*)d_in[3];
  const float* gamma = (const float*)d_in[4];
  const float* beta  = (const float*)d_in[5];
  float* out = (float*)d_out;
  char* ws = (char*)d_ws;
  // workspace layout (34 MB total); xn reused for Vt, v reused for attn_out
  u16* xn    = (u16*)(ws);                    // 8 MB   (dead after gemm_qkv -> Vt)
  u16* wqkvT = (u16*)(ws + 8388608);          // 1.5 MB
  u16* woutT = (u16*)(ws + 9961472);          // 0.5 MB
  u16* q     = (u16*)(ws + 10485760);         // 8 MB
  u16* k     = (u16*)(ws + 18874368);         // 8 MB
  u16* v     = (u16*)(ws + 27262976);         // 8 MB   (dead after repack -> attn_out)
  u16* vt       = xn;
  u16* attn_out = v;

  k_ln<<<2048, 256, 0, stream>>>(x, gamma, beta, xn);
  k_transpose_cast<<<dim3(48, 16), 256, 0, stream>>>(w_qkv, wqkvT, 512, 1536);
  k_transpose_cast<<<dim3(16, 16), 256, 0, stream>>>(w_out, woutT, 512, 512);
  k_gemm<0><<<64 * 12, 256, 0, stream>>>(xn, wqkvT, 1536, q, k, v, nullptr, nullptr, nullptr);
  k_repack_vt<<<dim3(64, 16), 256, 0, stream>>>(v, vt);
  k_attn<<<1024, 256, 0, stream>>>(q, k, vt, attn_out);
  k_gemm<1><<<64 * 4, 256, 0, stream>>>(attn_out, woutT, 512, nullptr, nullptr, nullptr, b_out, x, out);
}

// Round 2
// 157.568 us; speedup vs baseline: 1.2117x; 1.2117x over previous
//
#include <hip/hip_runtime.h>

typedef __attribute__((ext_vector_type(8))) short bh8;   // 8 bf16 (4 VGPRs)
typedef __attribute__((ext_vector_type(4))) short bh4;   // 4 bf16 (2 VGPRs)
typedef __attribute__((ext_vector_type(4))) float f32x4; // 4 fp32 acc
typedef unsigned short u16;

#define MFMA16 __builtin_amdgcn_mfma_f32_16x16x32_bf16

#if __has_builtin(__builtin_amdgcn_exp2f)
#define EXP2(x) __builtin_amdgcn_exp2f(x)
#else
#define EXP2(x) exp2f(x)
#endif

// softmax scale folded with log2(e): exp((s-m)*0.125) = exp2(s*C - m*C)
#define CEXP 0.18033688011112042f

__device__ __forceinline__ u16 f2bf(float f) {
  union { float f; unsigned u; } v; v.f = f;
  unsigned r = v.u + 0x7fffu + ((v.u >> 16) & 1u);
  return (u16)(r >> 16);
}

__device__ __forceinline__ void gload16(void* lds, const void* g) {
  __builtin_amdgcn_global_load_lds(
      (const __attribute__((address_space(1))) unsigned int*)g,
      (__attribute__((address_space(3))) unsigned int*)lds, 16, 0, 0);
}

// ---------------- LayerNorm: one wave per row of 512 fp32 -> bf16 ----------
__global__ __launch_bounds__(256) void k_ln(const float* __restrict__ x,
                                            const float* __restrict__ gamma,
                                            const float* __restrict__ beta,
                                            u16* __restrict__ xn) {
  int row  = blockIdx.x * 4 + (threadIdx.x >> 6);
  int lane = threadIdx.x & 63;
  const float4* xr = (const float4*)(x + row * 512);
  float4 a = xr[lane * 2], b = xr[lane * 2 + 1];
  float s  = a.x + a.y + a.z + a.w + b.x + b.y + b.z + b.w;
  float ss = a.x*a.x + a.y*a.y + a.z*a.z + a.w*a.w
           + b.x*b.x + b.y*b.y + b.z*b.z + b.w*b.w;
#pragma unroll
  for (int m = 1; m < 64; m <<= 1) { s += __shfl_xor(s, m, 64); ss += __shfl_xor(ss, m, 64); }
  float mu  = s * (1.0f / 512.0f);
  float var = ss * (1.0f / 512.0f) - mu * mu;
  float rstd = rsqrtf(var + 1e-5f);
  const float4* g4 = (const float4*)gamma;
  const float4* b4 = (const float4*)beta;
  float4 g0 = g4[lane * 2], g1 = g4[lane * 2 + 1];
  float4 e0 = b4[lane * 2], e1 = b4[lane * 2 + 1];
  bh8 ov;
  ov[0] = (short)f2bf((a.x - mu) * rstd * g0.x + e0.x);
  ov[1] = (short)f2bf((a.y - mu) * rstd * g0.y + e0.y);
  ov[2] = (short)f2bf((a.z - mu) * rstd * g0.z + e0.z);
  ov[3] = (short)f2bf((a.w - mu) * rstd * g0.w + e0.w);
  ov[4] = (short)f2bf((b.x - mu) * rstd * g1.x + e1.x);
  ov[5] = (short)f2bf((b.y - mu) * rstd * g1.y + e1.y);
  ov[6] = (short)f2bf((b.z - mu) * rstd * g1.z + e1.z);
  ov[7] = (short)f2bf((b.w - mu) * rstd * g1.w + e1.w);
  *(bh8*)(xn + row * 512 + lane * 8) = ov;
}

// -------- transpose + cast: in (R,C) f32 row-major -> out (C,R) bf16 -------
__global__ __launch_bounds__(256) void k_transpose_cast(const float* __restrict__ in,
                                                        u16* __restrict__ out,
                                                        int R, int C) {
  __shared__ float tile[32][33];
  int c0 = blockIdx.x * 32, r0 = blockIdx.y * 32;
  int tx = threadIdx.x & 31, ty = threadIdx.x >> 5;
#pragma unroll
  for (int i = 0; i < 32; i += 8)
    tile[ty + i][tx] = in[(r0 + ty + i) * C + (c0 + tx)];
  __syncthreads();
#pragma unroll
  for (int i = 0; i < 32; i += 8)
    out[(c0 + ty + i) * R + (r0 + tx)] = f2bf(tile[tx][ty + i]);
}

// ---------------- V [bh][t][d] -> Vt [bh][d][t] ----------------------------
__global__ __launch_bounds__(256) void k_repack_vt(const u16* __restrict__ V,
                                                   u16* __restrict__ Vt) {
  __shared__ u16 tile[64 * 64];
  int bh = blockIdx.y;
  int t0 = blockIdx.x * 64;
  int tid = threadIdx.x;
  const u16* src = V + (bh * 4096 + t0) * 64;
#pragma unroll
  for (int j = 0; j < 2; ++j)
    *(bh8*)&tile[(j * 256 + tid) * 8] = *(const bh8*)(src + (j * 256 + tid) * 8);
  __syncthreads();
  int d = tid >> 2, ts = (tid & 3) * 16;
  bh8 o0, o1;
#pragma unroll
  for (int e = 0; e < 8; ++e) {
    o0[e] = (short)tile[(ts + e) * 64 + d];
    o1[e] = (short)tile[(ts + 8 + e) * 64 + d];
  }
  u16* dst = Vt + (bh * 64 + d) * 4096 + t0 + ts;
  *(bh8*)dst = o0;
  *(bh8*)(dst + 8) = o1;
}

// ---------------- GEMM: A (M,512) bf16 @ Bt (N,512) bf16 -------------------
template <int EPI>
__global__ __launch_bounds__(256) void k_gemm(const u16* __restrict__ A,
                                              const u16* __restrict__ Bt,
                                              int N,
                                              u16* __restrict__ q, u16* __restrict__ kk, u16* __restrict__ v,
                                              const float* __restrict__ bias,
                                              const float* __restrict__ resid,
                                              float* __restrict__ outp) {
  constexpr int K = 512, BM = 128, BK = 64;
  __shared__ u16 Al[BM * BK];
  __shared__ u16 Bl[BM * BK];
  int nBN = N / 128;
  int m0 = (blockIdx.x / nBN) * BM;
  int n0 = (blockIdx.x % nBN) * 128;
  int tid = threadIdx.x, lane = tid & 63, w = tid >> 6;
  int l16 = lane & 15, lh = lane >> 4;
  int wm = (w >> 1) * 64, wn = (w & 1) * 64;
  const u16* Ab = A + m0 * K;
  const u16* Bb = Bt + n0 * K;
  f32x4 acc[4][4];
#pragma unroll
  for (int i = 0; i < 4; ++i)
#pragma unroll
    for (int j = 0; j < 4; ++j) acc[i][j] = (f32x4){0.f, 0.f, 0.f, 0.f};
  int srow = tid >> 3, schunk = tid & 7;
  for (int k0 = 0; k0 < K; k0 += BK) {
    __syncthreads();
#pragma unroll
    for (int j = 0; j < 4; ++j) {
      int r = j * 32 + srow;
      int sc = ((schunk ^ (r & 7)) << 3);
      gload16((char*)Al + j * 4096 + tid * 16, Ab + r * K + k0 + sc);
      gload16((char*)Bl + j * 4096 + tid * 16, Bb + r * K + k0 + sc);
    }
    __syncthreads();
#pragma unroll
    for (int c = 0; c < 2; ++c) {
      bh8 af[4], bf[4];
#pragma unroll
      for (int i = 0; i < 4; ++i) {
        int ra = wm + i * 16 + l16;
        af[i] = *(const bh8*)&Al[ra * 64 + ((c * 32 + lh * 8) ^ ((ra & 7) << 3))];
        int rb = wn + i * 16 + l16;
        bf[i] = *(const bh8*)&Bl[rb * 64 + ((c * 32 + lh * 8) ^ ((rb & 7) << 3))];
      }
#pragma unroll
      for (int mi = 0; mi < 4; ++mi)
#pragma unroll
        for (int ni = 0; ni < 4; ++ni)
          acc[mi][ni] = MFMA16(af[mi], bf[ni], acc[mi][ni], 0, 0, 0);
    }
  }
  if (EPI == 0) {
#pragma unroll
    for (int mi = 0; mi < 4; ++mi)
#pragma unroll
      for (int ni = 0; ni < 4; ++ni) {
        int col = n0 + wn + ni * 16 + l16;
        int s = col >> 9, h = (col >> 6) & 7, d = col & 63;
        u16* base = (s == 0 ? q : (s == 1 ? kk : v));
#pragma unroll
        for (int j = 0; j < 4; ++j) {
          int row = m0 + wm + mi * 16 + lh * 4 + j;
          int b = row >> 12, t = row & 4095;
          base[(((b << 3) + h) * 4096 + t) * 64 + d] = f2bf(acc[mi][ni][j]);
        }
      }
  } else {
#pragma unroll
    for (int mi = 0; mi < 4; ++mi)
#pragma unroll
      for (int ni = 0; ni < 4; ++ni) {
        int col = n0 + wn + ni * 16 + l16;
        float bo = bias[col];
#pragma unroll
        for (int j = 0; j < 4; ++j) {
          int row = m0 + wm + mi * 16 + lh * 4 + j;
          outp[row * 512 + col] = acc[mi][ni][j] + bo + resid[row * 512 + col];
        }
      }
  }
}

// ---------------- Flash attention, causal, hd=64, swapped-QK^T -------------
// block = 4 waves; Q tile = 64 rows (16/wave); KV tile = 64.
// S^T = mfma(K, Q): lane (l16,lh) holds S[tk=f*16+lh*4+j][q=l16] -> each lane
// owns ONE q-row => softmax row-reduce = in-lane chain + shfl_xor(16,32).
// P stays in registers as the PV A-fragment; PV k-order is the permutation
// pi(32m + lh*8 + e) = (2m+(e>>2))*16 + lh*4 + (e&3), matched on the V side
// by two b64 reads per fragment from the (unchanged, swizzled) V tile.
// O accumulator rows are q=lh*4+j => rescale factors cross domains via
// 4 ds_bpermute (__shfl with computed lane).
#define SV(e, r) (((((e) >> 3) ^ ((r) & 7)) << 3) | ((e) & 7))

__global__ __launch_bounds__(256) void k_attn(const u16* __restrict__ Q,
                                              const u16* __restrict__ Kg,
                                              const u16* __restrict__ Vt,
                                              u16* __restrict__ O) {
  __shared__ u16 Kl[64 * 64];   // [tk][d], chunk-swizzled
  __shared__ u16 Vl[64 * 64];   // [d][t],  chunk-swizzled
  int bh = blockIdx.x & 15;
  int qi = 63 - (blockIdx.x >> 4);   // descending length for load balance
  int tid = threadIdx.x, lane = tid & 63, w = tid >> 6;
  int l16 = lane & 15, lh = lane >> 4;
  const u16* Qb = Q + bh * 4096 * 64;
  const u16* Kb = Kg + bh * 4096 * 64;
  const u16* Vb = Vt + bh * 64 * 4096;
  int q0 = qi * 64;
  int myq = q0 + w * 16 + l16;       // this lane's softmax q-row
  bh8 qf0 = *(const bh8*)(Qb + myq * 64 + lh * 8);
  bh8 qf1 = *(const bh8*)(Qb + myq * 64 + 32 + lh * 8);
  float m_ = -3e38f, l_ = 0.f;
  f32x4 acc[4];                      // O[q=lh*4+j][d=dn*16+l16]
#pragma unroll
  for (int dn = 0; dn < 4; ++dn) acc[dn] = (f32x4){0.f, 0.f, 0.f, 0.f};
  int srow = tid >> 3, schunk = tid & 7;
  for (int kt = 0; kt <= qi; ++kt) {
    int k0 = kt * 64;
    __syncthreads();
#pragma unroll
    for (int j = 0; j < 2; ++j) {
      int r = j * 32 + srow;
      int sc = ((schunk ^ (r & 7)) << 3);
      gload16((char*)Kl + j * 4096 + tid * 16, Kb + (k0 + r) * 64 + sc);
      gload16((char*)Vl + j * 4096 + tid * 16, Vb + r * 4096 + k0 + sc);
    }
    __syncthreads();
    // ---- S^T = K @ Q^T ----
    f32x4 s[4];
    __builtin_amdgcn_s_setprio(1);
#pragma unroll
    for (int f = 0; f < 4; ++f) {
      int r = f * 16 + l16;
      bh8 kf0 = *(const bh8*)&Kl[r * 64 + ((lh * 8) ^ ((r & 7) << 3))];
      bh8 kf1 = *(const bh8*)&Kl[r * 64 + ((32 + lh * 8) ^ ((r & 7) << 3))];
      f32x4 z = (f32x4){0.f, 0.f, 0.f, 0.f};
      z = MFMA16(kf0, qf0, z, 0, 0, 0);
      z = MFMA16(kf1, qf1, z, 0, 0, 0);
      s[f] = z;
    }
    __builtin_amdgcn_s_setprio(0);
    if (kt == qi) {
#pragma unroll
      for (int f = 0; f < 4; ++f)
#pragma unroll
        for (int j = 0; j < 4; ++j) {
          int tk = k0 + f * 16 + lh * 4 + j;
          if (tk > myq) s[f][j] = -3e38f;
        }
    }
    // ---- in-register online softmax ----
    float mx = s[0][0];
#pragma unroll
    for (int f = 0; f < 4; ++f)
#pragma unroll
      for (int j = 0; j < 4; ++j) mx = fmaxf(mx, s[f][j]);
    mx = fmaxf(mx, __shfl_xor(mx, 16, 64));
    mx = fmaxf(mx, __shfl_xor(mx, 32, 64));
    float nm = fmaxf(m_, mx);
    float nmC = nm * CEXP;
    float rs = 0.f;
    bh8 pa0, pa1;   // PV A-frags: pa[m][(f&1)*4+j] = P(f=2m+(f&1), j)
#pragma unroll
    for (int f = 0; f < 4; ++f)
#pragma unroll
      for (int j = 0; j < 4; ++j) {
        float p = EXP2(fmaf(s[f][j], CEXP, -nmC));
        rs += p;
        if (f < 2) pa0[(f & 1) * 4 + j] = (short)f2bf(p);
        else       pa1[(f & 1) * 4 + j] = (short)f2bf(p);
      }
    rs += __shfl_xor(rs, 16, 64);
    rs += __shfl_xor(rs, 32, 64);
    if (__any(nm > m_)) {               // defer-max: skip rescale if no growth
      float fac = EXP2(fmaf(m_, CEXP, -nmC));
      l_ = l_ * fac + rs;
      float f0 = __shfl(fac, lh * 4 + 0, 64);
      float f1 = __shfl(fac, lh * 4 + 1, 64);
      float f2 = __shfl(fac, lh * 4 + 2, 64);
      float f3 = __shfl(fac, lh * 4 + 3, 64);
#pragma unroll
      for (int dn = 0; dn < 4; ++dn) {
        acc[dn][0] *= f0; acc[dn][1] *= f1;
        acc[dn][2] *= f2; acc[dn][3] *= f3;
      }
    } else {
      l_ += rs;
    }
    m_ = nm;
    // ---- PV: O += P @ V ----
    __builtin_amdgcn_s_setprio(1);
#pragma unroll
    for (int dn = 0; dn < 4; ++dn) {
      int r = dn * 16 + l16;
      bh4 lo0 = *(const bh4*)&Vl[r * 64 + SV(lh * 4, r)];
      bh4 hi0 = *(const bh4*)&Vl[r * 64 + SV(16 + lh * 4, r)];
      bh4 lo1 = *(const bh4*)&Vl[r * 64 + SV(32 + lh * 4, r)];
      bh4 hi1 = *(const bh4*)&Vl[r * 64 + SV(48 + lh * 4, r)];
      bh8 vb0, vb1;
      vb0[0] = lo0[0]; vb0[1] = lo0[1]; vb0[2] = lo0[2]; vb0[3] = lo0[3];
      vb0[4] = hi0[0]; vb0[5] = hi0[1]; vb0[6] = hi0[2]; vb0[7] = hi0[3];
      vb1[0] = lo1[0]; vb1[1] = lo1[1]; vb1[2] = lo1[2]; vb1[3] = lo1[3];
      vb1[4] = hi1[0]; vb1[5] = hi1[1]; vb1[6] = hi1[2]; vb1[7] = hi1[3];
      acc[dn] = MFMA16(pa0, vb0, acc[dn], 0, 0, 0);
      acc[dn] = MFMA16(pa1, vb1, acc[dn], 0, 0, 0);
    }
    __builtin_amdgcn_s_setprio(0);
  }
  // ---- epilogue: O[q][d] / l_ ----
  float inv = 1.0f / l_;
  float i0 = __shfl(inv, lh * 4 + 0, 64);
  float i1 = __shfl(inv, lh * 4 + 1, 64);
  float i2 = __shfl(inv, lh * 4 + 2, 64);
  float i3 = __shfl(inv, lh * 4 + 3, 64);
  int b = bh >> 3, h = bh & 7;
#pragma unroll
  for (int j = 0; j < 4; ++j) {
    float iv = (j == 0 ? i0 : j == 1 ? i1 : j == 2 ? i2 : i3);
    int t = q0 + w * 16 + lh * 4 + j;
#pragma unroll
    for (int dn = 0; dn < 4; ++dn)
      O[(b * 4096 + t) * 512 + h * 64 + dn * 16 + l16] = f2bf(acc[dn][j] * iv);
  }
}

extern "C" void kernel_launch(void* const* d_in, const int* in_sizes, int n_in,
                              void* d_out, int out_size, void* d_ws, size_t ws_size,
                              hipStream_t stream) {
  const float* x     = (const float*)d_in[0];
  const float* w_qkv = (const float*)d_in[1];
  const float* w_out = (const float*)d_in[2];
  const float* b_out = (const float*)d_in[3];
  const float* gamma = (const float*)d_in[4];
  const float* beta  = (const float*)d_in[5];
  float* out = (float*)d_out;
  char* ws = (char*)d_ws;
  u16* xn    = (u16*)(ws);                    // 8 MB   (dead after gemm_qkv -> Vt)
  u16* wqkvT = (u16*)(ws + 8388608);          // 1.5 MB
  u16* woutT = (u16*)(ws + 9961472);          // 0.5 MB
  u16* q     = (u16*)(ws + 10485760);         // 8 MB
  u16* k     = (u16*)(ws + 18874368);         // 8 MB
  u16* v     = (u16*)(ws + 27262976);         // 8 MB   (dead after repack -> attn_out)
  u16* vt       = xn;
  u16* attn_out = v;

  k_ln<<<2048, 256, 0, stream>>>(x, gamma, beta, xn);
  k_transpose_cast<<<dim3(48, 16), 256, 0, stream>>>(w_qkv, wqkvT, 512, 1536);
  k_transpose_cast<<<dim3(16, 16), 256, 0, stream>>>(w_out, woutT, 512, 512);
  k_gemm<0><<<64 * 12, 256, 0, stream>>>(xn, wqkvT, 1536, q, k, v, nullptr, nullptr, nullptr);
  k_repack_vt<<<dim3(64, 16), 256, 0, stream>>>(v, vt);
  k_attn<<<1024, 256, 0, stream>>>(q, k, vt, attn_out);
  k_gemm<1><<<64 * 4, 256, 0, stream>>>(attn_out, woutT, 512, nullptr, nullptr, nullptr, b_out, x, out);
}

// Round 4
// 149.196 us; speedup vs baseline: 1.2797x; 1.0561x over previous
//
#include <hip/hip_runtime.h>

typedef __attribute__((ext_vector_type(8))) short bh8;   // 8 bf16 (4 VGPRs)
typedef __attribute__((ext_vector_type(4))) float f32x4; // 4 fp32 acc
typedef unsigned short u16;

#define MFMA16 __builtin_amdgcn_mfma_f32_16x16x32_bf16

#if __has_builtin(__builtin_amdgcn_exp2f)
#define EXP2(x) __builtin_amdgcn_exp2f(x)
#else
#define EXP2(x) exp2f(x)
#endif

// softmax scale folded with log2(e): exp((s-m)*0.125) = exp2(s*C - m*C)
#define CEXP 0.18033688011112042f

__device__ __forceinline__ u16 f2bf(float f) {
  union { float f; unsigned u; } v; v.f = f;
  unsigned r = v.u + 0x7fffu + ((v.u >> 16) & 1u);
  return (u16)(r >> 16);
}

// v_cvt_pk_bf16_f32: dst.lo16 = bf16(lo), dst.hi16 = bf16(hi), RNE
__device__ __forceinline__ unsigned cvtpk(float lo, float hi) {
  unsigned r;
  asm("v_cvt_pk_bf16_f32 %0, %1, %2" : "=v"(r) : "v"(lo), "v"(hi));
  return r;
}

__device__ __forceinline__ void gload16(void* lds, const void* g) {
  __builtin_amdgcn_global_load_lds(
      (const __attribute__((address_space(1))) unsigned int*)g,
      (__attribute__((address_space(3))) unsigned int*)lds, 16, 0, 0);
}

// ---------------- LayerNorm: one wave per row of 512 fp32 -> bf16 ----------
__global__ __launch_bounds__(256) void k_ln(const float* __restrict__ x,
                                            const float* __restrict__ gamma,
                                            const float* __restrict__ beta,
                                            u16* __restrict__ xn) {
  int row  = blockIdx.x * 4 + (threadIdx.x >> 6);
  int lane = threadIdx.x & 63;
  const float4* xr = (const float4*)(x + row * 512);
  float4 a = xr[lane * 2], b = xr[lane * 2 + 1];
  float s  = a.x + a.y + a.z + a.w + b.x + b.y + b.z + b.w;
  float ss = a.x*a.x + a.y*a.y + a.z*a.z + a.w*a.w
           + b.x*b.x + b.y*b.y + b.z*b.z + b.w*b.w;
#pragma unroll
  for (int m = 1; m < 64; m <<= 1) { s += __shfl_xor(s, m, 64); ss += __shfl_xor(ss, m, 64); }
  float mu  = s * (1.0f / 512.0f);
  float var = ss * (1.0f / 512.0f) - mu * mu;
  float rstd = rsqrtf(var + 1e-5f);
  const float4* g4 = (const float4*)gamma;
  const float4* b4 = (const float4*)beta;
  float4 g0 = g4[lane * 2], g1 = g4[lane * 2 + 1];
  float4 e0 = b4[lane * 2], e1 = b4[lane * 2 + 1];
  bh8 ov;
  ov[0] = (short)f2bf((a.x - mu) * rstd * g0.x + e0.x);
  ov[1] = (short)f2bf((a.y - mu) * rstd * g0.y + e0.y);
  ov[2] = (short)f2bf((a.z - mu) * rstd * g0.z + e0.z);
  ov[3] = (short)f2bf((a.w - mu) * rstd * g0.w + e0.w);
  ov[4] = (short)f2bf((b.x - mu) * rstd * g1.x + e1.x);
  ov[5] = (short)f2bf((b.y - mu) * rstd * g1.y + e1.y);
  ov[6] = (short)f2bf((b.z - mu) * rstd * g1.z + e1.z);
  ov[7] = (short)f2bf((b.w - mu) * rstd * g1.w + e1.w);
  *(bh8*)(xn + row * 512 + lane * 8) = ov;
}

// -------- transpose + cast: in (R,C) f32 row-major -> out (C,R) bf16 -------
__global__ __launch_bounds__(256) void k_transpose_cast(const float* __restrict__ in,
                                                        u16* __restrict__ out,
                                                        int R, int C) {
  __shared__ float tile[32][33];
  int c0 = blockIdx.x * 32, r0 = blockIdx.y * 32;
  int tx = threadIdx.x & 31, ty = threadIdx.x >> 5;
#pragma unroll
  for (int i = 0; i < 32; i += 8)
    tile[ty + i][tx] = in[(r0 + ty + i) * C + (c0 + tx)];
  __syncthreads();
#pragma unroll
  for (int i = 0; i < 32; i += 8)
    out[(c0 + ty + i) * R + (r0 + tx)] = f2bf(tile[tx][ty + i]);
}

// ---------------- V [bh][t][d] -> Vt [bh][d][t] ----------------------------
__global__ __launch_bounds__(256) void k_repack_vt(const u16* __restrict__ V,
                                                   u16* __restrict__ Vt) {
  __shared__ u16 tile[64 * 64];
  int bh = blockIdx.y;
  int t0 = blockIdx.x * 64;
  int tid = threadIdx.x;
  const u16* src = V + (bh * 4096 + t0) * 64;
#pragma unroll
  for (int j = 0; j < 2; ++j)
    *(bh8*)&tile[(j * 256 + tid) * 8] = *(const bh8*)(src + (j * 256 + tid) * 8);
  __syncthreads();
  int d = tid >> 2, ts = (tid & 3) * 16;
  bh8 o0, o1;
#pragma unroll
  for (int e = 0; e < 8; ++e) {
    o0[e] = (short)tile[(ts + e) * 64 + d];
    o1[e] = (short)tile[(ts + 8 + e) * 64 + d];
  }
  u16* dst = Vt + (bh * 64 + d) * 4096 + t0 + ts;
  *(bh8*)dst = o0;
  *(bh8*)(dst + 8) = o1;
}

// ---------------- GEMM: A (M,512) bf16 @ Bt (N,512) bf16 -------------------
template <int EPI>
__global__ __launch_bounds__(256) void k_gemm(const u16* __restrict__ A,
                                              const u16* __restrict__ Bt,
                                              int N,
                                              u16* __restrict__ q, u16* __restrict__ kk, u16* __restrict__ v,
                                              const float* __restrict__ bias,
                                              const float* __restrict__ resid,
                                              float* __restrict__ outp) {
  constexpr int K = 512, BM = 128, BK = 64;
  __shared__ u16 Al[BM * BK];
  __shared__ u16 Bl[BM * BK];
  int nBN = N / 128;
  int m0 = (blockIdx.x / nBN) * BM;
  int n0 = (blockIdx.x % nBN) * 128;
  int tid = threadIdx.x, lane = tid & 63, w = tid >> 6;
  int l16 = lane & 15, lh = lane >> 4;
  int wm = (w >> 1) * 64, wn = (w & 1) * 64;
  const u16* Ab = A + m0 * K;
  const u16* Bb = Bt + n0 * K;
  f32x4 acc[4][4];
#pragma unroll
  for (int i = 0; i < 4; ++i)
#pragma unroll
    for (int j = 0; j < 4; ++j) acc[i][j] = (f32x4){0.f, 0.f, 0.f, 0.f};
  int srow = tid >> 3, schunk = tid & 7;
  for (int k0 = 0; k0 < K; k0 += BK) {
    __syncthreads();
#pragma unroll
    for (int j = 0; j < 4; ++j) {
      int r = j * 32 + srow;
      int sc = ((schunk ^ (r & 7)) << 3);
      gload16((char*)Al + j * 4096 + tid * 16, Ab + r * K + k0 + sc);
      gload16((char*)Bl + j * 4096 + tid * 16, Bb + r * K + k0 + sc);
    }
    __syncthreads();
#pragma unroll
    for (int c = 0; c < 2; ++c) {
      bh8 af[4], bf[4];
#pragma unroll
      for (int i = 0; i < 4; ++i) {
        int ra = wm + i * 16 + l16;
        af[i] = *(const bh8*)&Al[ra * 64 + ((c * 32 + lh * 8) ^ ((ra & 7) << 3))];
        int rb = wn + i * 16 + l16;
        bf[i] = *(const bh8*)&Bl[rb * 64 + ((c * 32 + lh * 8) ^ ((rb & 7) << 3))];
      }
#pragma unroll
      for (int mi = 0; mi < 4; ++mi)
#pragma unroll
        for (int ni = 0; ni < 4; ++ni)
          acc[mi][ni] = MFMA16(af[mi], bf[ni], acc[mi][ni], 0, 0, 0);
    }
  }
  if (EPI == 0) {
#pragma unroll
    for (int mi = 0; mi < 4; ++mi)
#pragma unroll
      for (int ni = 0; ni < 4; ++ni) {
        int col = n0 + wn + ni * 16 + l16;
        int s = col >> 9, h = (col >> 6) & 7, d = col & 63;
        u16* base = (s == 0 ? q : (s == 1 ? kk : v));
#pragma unroll
        for (int j = 0; j < 4; ++j) {
          int row = m0 + wm + mi * 16 + lh * 4 + j;
          int b = row >> 12, t = row & 4095;
          base[(((b << 3) + h) * 4096 + t) * 64 + d] = f2bf(acc[mi][ni][j]);
        }
      }
  } else {
#pragma unroll
    for (int mi = 0; mi < 4; ++mi)
#pragma unroll
      for (int ni = 0; ni < 4; ++ni) {
        int col = n0 + wn + ni * 16 + l16;
        float bo = bias[col];
#pragma unroll
        for (int j = 0; j < 4; ++j) {
          int row = m0 + wm + mi * 16 + lh * 4 + j;
          outp[row * 512 + col] = acc[mi][ni][j] + bo + resid[row * 512 + col];
        }
      }
  }
}

// ---------------- Flash attention, causal, hd=64, swapped-QK^T -------------
// block = 4 waves; Q tile = 64 rows (16/wave); KV tile = 64.
// S^T = mfma(K, Q): lane (l16,lh) holds S[tk=f*16+lh*4+j][q=l16] -> each lane
// owns ONE q-row => softmax row-reduce = in-lane trees + shfl_xor(16,32).
// P path: cvt_pk pairs -> 4 ds_write_b64 into a per-wave 2KB LDS strip laid
// out as the NATURAL A-fragment order (tk = 32m + lh*8 + e), XOR-swizzled
// (row&7)<<3 elems; read back as 2 ds_read_b128. Wave-private => no barrier.
// V fragments are then plain bh8 reads (same conflict-free pattern as K).
// O accumulator rows are q=lh*4+j => rescale factors cross domains via
// 4 ds_bpermute (__shfl with computed lane), only on rescaling tiles.
__global__ __launch_bounds__(256) void k_attn(const u16* __restrict__ Q,
                                              const u16* __restrict__ Kg,
                                              const u16* __restrict__ Vt,
                                              u16* __restrict__ O) {
  __shared__ u16 Kl[64 * 64];   // [tk][d], chunk-swizzled
  __shared__ u16 Vl[64 * 64];   // [d][t],  chunk-swizzled
  __shared__ u16 Pl[4 * 1024];  // per-wave 16 q-rows x 64 tk, swizzled
  int bh = blockIdx.x & 15;
  int qi = 63 - (blockIdx.x >> 4);   // descending length for load balance
  int tid = threadIdx.x, lane = tid & 63, w = tid >> 6;
  int l16 = lane & 15, lh = lane >> 4;
  const u16* Qb = Q + bh * 4096 * 64;
  const u16* Kb = Kg + bh * 4096 * 64;
  const u16* Vb = Vt + bh * 64 * 4096;
  int q0 = qi * 64;
  int myq = q0 + w * 16 + l16;       // this lane's softmax q-row
  bh8 qf0 = *(const bh8*)(Qb + myq * 64 + lh * 8);
  bh8 qf1 = *(const bh8*)(Qb + myq * 64 + 32 + lh * 8);
  float m_ = -3e38f, l_ = 0.f;
  f32x4 acc[4];                      // O[q=lh*4+j][d=dn*16+l16]
#pragma unroll
  for (int dn = 0; dn < 4; ++dn) acc[dn] = (f32x4){0.f, 0.f, 0.f, 0.f};
  int srow = tid >> 3, schunk = tid & 7;
  u16* pw = Pl + w * 1024 + l16 * 64;   // this lane's q-row strip
  int pswz = (l16 & 7) << 3;
  for (int kt = 0; kt <= qi; ++kt) {
    int k0 = kt * 64;
    __syncthreads();
#pragma unroll
    for (int j = 0; j < 2; ++j) {
      int r = j * 32 + srow;
      int sc = ((schunk ^ (r & 7)) << 3);
      gload16((char*)Kl + j * 4096 + tid * 16, Kb + (k0 + r) * 64 + sc);
      gload16((char*)Vl + j * 4096 + tid * 16, Vb + r * 4096 + k0 + sc);
    }
    __syncthreads();
    // ---- S^T = K @ Q^T ----
    f32x4 s[4];
    __builtin_amdgcn_s_setprio(1);
#pragma unroll
    for (int f = 0; f < 4; ++f) {
      int r = f * 16 + l16;
      bh8 kf0 = *(const bh8*)&Kl[r * 64 + ((lh * 8) ^ ((r & 7) << 3))];
      bh8 kf1 = *(const bh8*)&Kl[r * 64 + ((32 + lh * 8) ^ ((r & 7) << 3))];
      f32x4 z = (f32x4){0.f, 0.f, 0.f, 0.f};
      z = MFMA16(kf0, qf0, z, 0, 0, 0);
      z = MFMA16(kf1, qf1, z, 0, 0, 0);
      s[f] = z;
    }
    __builtin_amdgcn_s_setprio(0);
    if (kt == qi) {
#pragma unroll
      for (int f = 0; f < 4; ++f)
#pragma unroll
        for (int j = 0; j < 4; ++j) {
          int tk = k0 + f * 16 + lh * 4 + j;
          if (tk > myq) s[f][j] = -3e38f;
        }
    }
    // ---- in-register online softmax (balanced trees) ----
    float m0 = fmaxf(fmaxf(s[0][0], s[0][1]), fmaxf(s[0][2], s[0][3]));
    float m1 = fmaxf(fmaxf(s[1][0], s[1][1]), fmaxf(s[1][2], s[1][3]));
    float m2 = fmaxf(fmaxf(s[2][0], s[2][1]), fmaxf(s[2][2], s[2][3]));
    float m3 = fmaxf(fmaxf(s[3][0], s[3][1]), fmaxf(s[3][2], s[3][3]));
    float mx = fmaxf(fmaxf(m0, m1), fmaxf(m2, m3));
    mx = fmaxf(mx, __shfl_xor(mx, 16, 64));
    mx = fmaxf(mx, __shfl_xor(mx, 32, 64));
    float nm = fmaxf(m_, mx);
    float nmC = nm * CEXP;
    float rs = 0.f;
#pragma unroll
    for (int f = 0; f < 4; ++f) {
      float p0 = EXP2(fmaf(s[f][0], CEXP, -nmC));
      float p1 = EXP2(fmaf(s[f][1], CEXP, -nmC));
      float p2 = EXP2(fmaf(s[f][2], CEXP, -nmC));
      float p3 = EXP2(fmaf(s[f][3], CEXP, -nmC));
      rs += (p0 + p1) + (p2 + p3);
      uint2 pk;
      pk.x = cvtpk(p0, p1);
      pk.y = cvtpk(p2, p3);
      *(uint2*)&pw[(f * 16 + lh * 4) ^ pswz] = pk;
    }
    rs += __shfl_xor(rs, 16, 64);
    rs += __shfl_xor(rs, 32, 64);
    if (__any(mx > m_)) {               // skip rescale only if NO lane grew
      float fac = EXP2(fmaf(m_, CEXP, -nmC));
      l_ = l_ * fac + rs;
      float f0 = __shfl(fac, lh * 4 + 0, 64);
      float f1 = __shfl(fac, lh * 4 + 1, 64);
      float f2 = __shfl(fac, lh * 4 + 2, 64);
      float f3 = __shfl(fac, lh * 4 + 3, 64);
#pragma unroll
      for (int dn = 0; dn < 4; ++dn) {
        acc[dn][0] *= f0; acc[dn][1] *= f1;
        acc[dn][2] *= f2; acc[dn][3] *= f3;
      }
    } else {
      l_ += rs;
    }
    m_ = nm;
    // ---- PV: O += P @ V  (P via per-wave LDS, natural k-order) ----
    bh8 pa0 = *(const bh8*)&pw[(lh * 8) ^ pswz];
    bh8 pa1 = *(const bh8*)&pw[(32 + lh * 8) ^ pswz];
    __builtin_amdgcn_s_setprio(1);
#pragma unroll
    for (int dn = 0; dn < 4; ++dn) {
      int r = dn * 16 + l16;
      const u16* vr = Vl + r * 64;
      bh8 vb0 = *(const bh8*)&vr[(lh * 8) ^ ((r & 7) << 3)];
      bh8 vb1 = *(const bh8*)&vr[(32 + lh * 8) ^ ((r & 7) << 3)];
      acc[dn] = MFMA16(pa0, vb0, acc[dn], 0, 0, 0);
      acc[dn] = MFMA16(pa1, vb1, acc[dn], 0, 0, 0);
    }
    __builtin_amdgcn_s_setprio(0);
  }
  // ---- epilogue: O[q][d] / l_ ----
  float inv = 1.0f / l_;
  float i0 = __shfl(inv, lh * 4 + 0, 64);
  float i1 = __shfl(inv, lh * 4 + 1, 64);
  float i2 = __shfl(inv, lh * 4 + 2, 64);
  float i3 = __shfl(inv, lh * 4 + 3, 64);
  int b = bh >> 3, h = bh & 7;
#pragma unroll
  for (int j = 0; j < 4; ++j) {
    float iv = (j == 0 ? i0 : j == 1 ? i1 : j == 2 ? i2 : i3);
    int t = q0 + w * 16 + lh * 4 + j;
#pragma unroll
    for (int dn = 0; dn < 4; ++dn)
      O[(b * 4096 + t) * 512 + h * 64 + dn * 16 + l16] = f2bf(acc[dn][j] * iv);
  }
}

extern "C" void kernel_launch(void* const* d_in, const int* in_sizes, int n_in,
                              void* d_out, int out_size, void* d_ws, size_t ws_size,
                              hipStream_t stream) {
  const float* x     = (const float*)d_in[0];
  const float* w_qkv = (const float*)d_in[1];
  const float* w_out = (const float*)d_in[2];
  const float* b_out = (const float*)d_in[3];
  const float* gamma = (const float*)d_in[4];
  const float* beta  = (const float*)d_in[5];
  float* out = (float*)d_out;
  char* ws = (char*)d_ws;
  u16* xn    = (u16*)(ws);                    // 8 MB   (dead after gemm_qkv -> Vt)
  u16* wqkvT = (u16*)(ws + 8388608);          // 1.5 MB
  u16* woutT = (u16*)(ws + 9961472);          // 0.5 MB
  u16* q     = (u16*)(ws + 10485760);         // 8 MB
  u16* k     = (u16*)(ws + 18874368);         // 8 MB
  u16* v     = (u16*)(ws + 27262976);         // 8 MB   (dead after repack -> attn_out)
  u16* vt       = xn;
  u16* attn_out = v;

  k_ln<<<2048, 256, 0, stream>>>(x, gamma, beta, xn);
  k_transpose_cast<<<dim3(48, 16), 256, 0, stream>>>(w_qkv, wqkvT, 512, 1536);
  k_transpose_cast<<<dim3(16, 16), 256, 0, stream>>>(w_out, woutT, 512, 512);
  k_gemm<0><<<64 * 12, 256, 0, stream>>>(xn, wqkvT, 1536, q, k, v, nullptr, nullptr, nullptr);
  k_repack_vt<<<dim3(64, 16), 256, 0, stream>>>(v, vt);
  k_attn<<<1024, 256, 0, stream>>>(q, k, vt, attn_out);
  k_gemm<1><<<64 * 4, 256, 0, stream>>>(attn_out, woutT, 512, nullptr, nullptr, nullptr, b_out, x, out);
}